// Round 1
// baseline (883.338 us; speedup 1.0000x reference)
//
#include <hip/hip_runtime.h>
#include <hip/hip_bf16.h>
#include <math.h>

#define B_ 2
#define T_ 512
#define D_ 64

// ---------------------------------------------------------------------------
// Kernel 0: suffix max/min pools.  cur0[b,i,:] = [max f[b,i..T-1], min f[b,i..T-1]]
// ---------------------------------------------------------------------------
__global__ void suffix_pool_kernel(const float* __restrict__ f,
                                   float* __restrict__ cur0) {
    const int b = blockIdx.x;
    const int d = threadIdx.x;  // 0..63
    float mx = -INFINITY;
    float mn = INFINITY;
    for (int i = T_ - 1; i >= 0; --i) {
        float v = f[((size_t)b * T_ + i) * D_ + d];
        mx = fmaxf(mx, v);
        mn = fminf(mn, v);
        cur0[((size_t)b * T_ + i) * 128 + d] = mx;
        cur0[((size_t)b * T_ + i) * 128 + 64 + d] = mn;
    }
}

// ---------------------------------------------------------------------------
// Layer kernel.  One block of 256 threads (4 waves) per output row (b,i).
//   li[b,i,j] = [ cur[b,j] (C floats), runmax f[b,i..j] (64), runmin (64) ]
//   h[j,o]    = sigmoid( li . W[:,o] + bias[o] )
//   out[b,i,o] = max_{j>=i} h[j,o]
// Wave g holds W rows [g*DIN/4, (g+1)*DIN/4) in registers (lane = o).
// li lives in LDS; broadcast float4 reads (conflict-free).
// ---------------------------------------------------------------------------
template <int C>
__global__ __launch_bounds__(256) void layer_kernel(
    const float* __restrict__ f,     // [B,T,64]
    const float* __restrict__ cur,   // [B,T,C]
    const float* __restrict__ W,     // [DIN,64]
    const float* __restrict__ bias,  // [64]
    float* __restrict__ out)         // [B,T,64]
{
    constexpr int DIN = C + 128;
    constexpr int DIN4 = DIN / 4;   // per-wave c-count (64 or 48)

    const int bx = blockIdx.x;      // 0..B*T-1, i-major so long rows start first
    const int i = bx >> 1;          // row index
    const int b = bx & 1;           // batch index
    const int tid = threadIdx.x;
    const int o = tid & 63;         // output channel
    const int g = tid >> 6;         // wave/group id 0..3

    __shared__ float li[DIN];
    __shared__ float part[4][64];

    // Load this wave's W slice into registers (coalesced).
    float wreg[DIN4];
#pragma unroll
    for (int k = 0; k < DIN4; ++k)
        wreg[k] = W[((size_t)(g * DIN4 + k)) * 64 + o];

    const float bo = bias[o];

    // Init running pools with f[b,i].
    if (tid < 64) {
        float v = f[((size_t)b * T_ + i) * D_ + tid];
        li[C + tid] = v;        // running max
        li[C + 64 + tid] = v;   // running min
    }

    float acc = 0.0f;  // sigmoid output is in (0,1), 0 is a safe -inf

    for (int j = i; j < T_; ++j) {
        // Update running max/min with f[b,j] (j==i already initialized).
        if (j > i && tid < 64) {
            float v = f[((size_t)b * T_ + j) * D_ + tid];
            li[C + tid] = fmaxf(li[C + tid], v);
            li[C + 64 + tid] = fminf(li[C + 64 + tid], v);
        }
        // Load current[b,j] into li[0..C).
        if (tid >= 128 && tid < 128 + C) {
            int c = tid - 128;
            li[c] = cur[((size_t)b * T_ + j) * C + c];
        }
        __syncthreads();

        // Partial dot over this wave's c-range (broadcast LDS reads).
        float p = 0.0f;
        const float4* lp = (const float4*)&li[g * DIN4];
#pragma unroll
        for (int k = 0; k < DIN4 / 4; ++k) {
            float4 v = lp[k];
            p += v.x * wreg[4 * k + 0];
            p += v.y * wreg[4 * k + 1];
            p += v.z * wreg[4 * k + 2];
            p += v.w * wreg[4 * k + 3];
        }
        part[g][o] = p;
        __syncthreads();

        if (tid < 64) {
            float s = part[0][o] + part[1][o] + part[2][o] + part[3][o] + bo;
            float h = 1.0f / (1.0f + __expf(-s));
            acc = fmaxf(acc, h);
        }
    }

    if (tid < 64)
        out[((size_t)b * T_ + i) * 64 + tid] = acc;
}

// ---------------------------------------------------------------------------
extern "C" void kernel_launch(void* const* d_in, const int* in_sizes, int n_in,
                              void* d_out, int out_size, void* d_ws, size_t ws_size,
                              hipStream_t stream) {
    const float* f  = (const float*)d_in[0];
    const float* W0 = (const float*)d_in[1];
    const float* b0 = (const float*)d_in[2];
    const float* W1 = (const float*)d_in[3];
    const float* b1 = (const float*)d_in[4];
    const float* W2 = (const float*)d_in[5];
    const float* b2 = (const float*)d_in[6];
    float* outp = (float*)d_out;

    float* cur0 = (float*)d_ws;                    // [B,T,128]
    float* cur1 = cur0 + (size_t)B_ * T_ * 128;    // [B,T,64]
    float* cur2 = cur1 + (size_t)B_ * T_ * 64;     // [B,T,64]

    suffix_pool_kernel<<<dim3(B_), dim3(64), 0, stream>>>(f, cur0);

    const int nrow = B_ * T_;
    layer_kernel<128><<<dim3(nrow), dim3(256), 0, stream>>>(f, cur0, W0, b0, cur1);
    layer_kernel<64 ><<<dim3(nrow), dim3(256), 0, stream>>>(f, cur1, W1, b1, cur2);
    layer_kernel<64 ><<<dim3(nrow), dim3(256), 0, stream>>>(f, cur2, W2, b2, outp);
}

// Round 2
// 340.844 us; speedup vs baseline: 2.5916x; 2.5916x over previous
//
#include <hip/hip_runtime.h>
#include <hip/hip_bf16.h>
#include <math.h>

#define B_ 2
#define T_ 512
#define D_ 64

typedef __attribute__((ext_vector_type(8))) short bf16x8;
typedef __attribute__((ext_vector_type(8))) unsigned short u16x8;
typedef __attribute__((ext_vector_type(4))) float f32x4;

static __device__ __forceinline__ unsigned short f2bf(float v) {
    __hip_bfloat16 h = __float2bfloat16(v);
    return *reinterpret_cast<unsigned short*>(&h);
}
static __device__ __forceinline__ float bf2f(unsigned short u) {
    return __uint_as_float(((unsigned)u) << 16);
}

// ---------------------------------------------------------------------------
// Sparse tables (bf16): tab[k][b][t][c] = max/min of f[b, t .. t+2^k-1, c]
// Levels 0..9.  Entries with t > T-2^k are junk (clamped) and never queried.
// ---------------------------------------------------------------------------
__global__ __launch_bounds__(512) void table_kernel(const float* __restrict__ f,
                                                    unsigned short* __restrict__ tmax,
                                                    unsigned short* __restrict__ tmin) {
    const int b = blockIdx.y;
    const int c0 = blockIdx.x * 16;
    const int t = threadIdx.x;
#pragma unroll
    for (int cc = 0; cc < 16; ++cc) {
        int c = c0 + cc;
        unsigned short u = f2bf(f[((b * T_ + t) << 6) + c]);
        tmax[((0 * B_ + b) * T_ + t) * 64 + c] = u;
        tmin[((0 * B_ + b) * T_ + t) * 64 + c] = u;
    }
    __threadfence_block();
    __syncthreads();
    for (int k = 1; k <= 9; ++k) {
        int half = 1 << (k - 1);
        int t2 = t + half; if (t2 > T_ - 1) t2 = T_ - 1;
#pragma unroll
        for (int cc = 0; cc < 16; ++cc) {
            int c = c0 + cc;
            unsigned short a = tmax[(((k - 1) * B_ + b) * T_ + t) * 64 + c];
            unsigned short x = tmax[(((k - 1) * B_ + b) * T_ + t2) * 64 + c];
            tmax[((k * B_ + b) * T_ + t) * 64 + c] = (bf2f(a) >= bf2f(x)) ? a : x;
            unsigned short a2 = tmin[(((k - 1) * B_ + b) * T_ + t) * 64 + c];
            unsigned short x2 = tmin[(((k - 1) * B_ + b) * T_ + t2) * 64 + c];
            tmin[((k * B_ + b) * T_ + t) * 64 + c] = (bf2f(a2) <= bf2f(x2)) ? a2 : x2;
        }
        __threadfence_block();
        __syncthreads();
    }
}

// ---------------------------------------------------------------------------
// Suffix pools (fp32): cur0[b,t,:] = [max f[b,t..T-1], min f[b,t..T-1]]
// Hillis-Steele suffix scan in LDS, one block per (channel, b).
// ---------------------------------------------------------------------------
__global__ __launch_bounds__(512) void suffix_kernel(const float* __restrict__ f,
                                                     float* __restrict__ cur0) {
    const int c = blockIdx.x, b = blockIdx.y;
    const int t = threadIdx.x;
    __shared__ float smax[512];
    __shared__ float smin[512];
    float v = f[((b * T_ + t) << 6) + c];
    smax[t] = v; smin[t] = v;
    __syncthreads();
    for (int off = 1; off < 512; off <<= 1) {
        float a = (t + off < 512) ? smax[t + off] : -1e30f;
        float m = (t + off < 512) ? smin[t + off] : 1e30f;
        __syncthreads();
        smax[t] = fmaxf(smax[t], a);
        smin[t] = fminf(smin[t], m);
        __syncthreads();
    }
    cur0[((b * T_ + t) << 7) + c] = smax[t];
    cur0[((b * T_ + t) << 7) + 64 + c] = smin[t];
}

// ---------------------------------------------------------------------------
// Pre-pack W[C : C+128][64] into MFMA B-fragment order (bf16):
// wf[layer][frag=kt*4+nt][lane][e] = W[C + kt*32 + (lane>>4)*8 + e][nt*16 + (lane&15)]
// ---------------------------------------------------------------------------
__global__ void wfrag_kernel(const float* __restrict__ W0, const float* __restrict__ W1,
                             const float* __restrict__ W2, unsigned short* __restrict__ wf) {
    const int layer = blockIdx.y;
    const int fr = blockIdx.x;      // kt*4+nt
    const int l = threadIdx.x;      // 64
    const float* W = (layer == 0) ? W0 : ((layer == 1) ? W1 : W2);
    const int Coff = (layer == 0) ? 128 : 64;
    const int kt = fr >> 2, nt = fr & 3;
#pragma unroll
    for (int e = 0; e < 8; ++e) {
        int row = Coff + kt * 32 + ((l >> 4) << 3) + e;
        int col = nt * 16 + (l & 15);
        wf[((layer * 16 + fr) * 64 + l) * 8 + e] = f2bf(W[row * 64 + col]);
    }
}

// ---------------------------------------------------------------------------
// g[b,t,o] = bias[o] + sum_c cur[b,t,c] * W[c][o];   also zeroes next out buf.
// ---------------------------------------------------------------------------
template <int C>
__global__ __launch_bounds__(256) void g_kernel(const float* __restrict__ cur,
                                                const float* __restrict__ W,
                                                const float* __restrict__ bias,
                                                float* __restrict__ g,
                                                float* __restrict__ outz) {
    const int bt = blockIdx.x * 4 + (threadIdx.x >> 6);   // 0..B*T-1
    const int o = threadIdx.x & 63;
    float s = bias[o];
    const float* cp = &cur[(size_t)bt * C];
#pragma unroll 8
    for (int c = 0; c < C; ++c)
        s = fmaf(cp[c], W[c * 64 + o], s);
    g[(bt << 6) + o] = s;
    outz[(bt << 6) + o] = 0.0f;
}

// ---------------------------------------------------------------------------
// Pair GEMM: block = (b, 2 i's, 32 j's) = 64 pairs x K=128 x N=64 outputs.
//   A[pair][k] = [rmax(i,j) 64ch | rmin(i,j) 64ch] from sparse tables (bf16)
//   s = A·Wr + g[b,j,:];  out[b,i,o] = atomicMax over sigmoid(max_j s)
// A staged in XOR-swizzled LDS; W pre-packed fragment-order in global.
// ---------------------------------------------------------------------------
__global__ __launch_bounds__(256) void pair_kernel(const unsigned short* __restrict__ tabmax,
                                                   const unsigned short* __restrict__ tabmin,
                                                   const unsigned short* __restrict__ wf,
                                                   const float* __restrict__ g,
                                                   float* __restrict__ out) {
    const int jt = blockIdx.x, it = blockIdx.y, b = blockIdx.z;
    const int i0 = it * 2, j0 = jt * 32;
    if (j0 + 31 < i0) return;   // tile entirely below diagonal

    const int tid = threadIdx.x;
    const int l = tid & 63, w = tid >> 6;

    __shared__ unsigned short Albs[64 * 128];   // [pair][128ch], XOR-swizzled
    __shared__ float gl[32][65];
    __shared__ float part[4][64];

    // B fragments: 16 x dwordx4 per lane, identical across waves (L1 hit)
    bf16x8 bfrag[16];
#pragma unroll
    for (int q = 0; q < 16; ++q)
        bfrag[q] = *reinterpret_cast<const bf16x8*>(&wf[(q * 64 + l) * 8]);

    // stage g tile [32 j][64 o]
#pragma unroll
    for (int q = 0; q < 8; ++q) {
        int x = q * 256 + tid;
        gl[x >> 6][x & 63] = g[(size_t)((b * T_ + j0) << 6) + x];
    }

    // build A tile: 64 pairs x 16 chunks of 8 channels
#pragma unroll
    for (int q = 0; q < 4; ++q) {
        int item = q * 256 + tid;            // 0..1023
        int p = item >> 4, c8 = item & 15;
        int pi = i0 + (p >> 5);
        int pj = j0 + (p & 31);
        int je = pj < pi ? pi : pj;          // clamp below-diagonal (masked later)
        int len = je - pi + 1;
        int k = 31 - __clz(len);
        int t2 = je + 1 - (1 << k);
        const unsigned short* tab = (c8 < 8) ? tabmax : tabmin;
        int cc = (c8 & 7) * 8;
        u16x8 va = *reinterpret_cast<const u16x8*>(&tab[(((k * B_ + b) * T_ + pi) << 6) + cc]);
        u16x8 vb = *reinterpret_cast<const u16x8*>(&tab[(((k * B_ + b) * T_ + t2) << 6) + cc]);
        u16x8 r;
#pragma unroll
        for (int e = 0; e < 8; ++e) {
            float fa = bf2f(va[e]), fb = bf2f(vb[e]);
            bool pick_a = (c8 < 8) ? (fa >= fb) : (fa <= fb);
            r[e] = pick_a ? va[e] : vb[e];
        }
        int addr = p * 128 + ((c8 * 8) ^ ((p & 7) << 3));   // ushort units
        *reinterpret_cast<u16x8*>(&Albs[addr]) = r;
    }
    __syncthreads();

    // GEMM: wave w owns pair strip [w*16, w*16+16)
    f32x4 acc[4];
#pragma unroll
    for (int nt = 0; nt < 4; ++nt) acc[nt] = (f32x4){0.f, 0.f, 0.f, 0.f};
    const int arow = w * 16 + (l & 15);
#pragma unroll
    for (int kt = 0; kt < 4; ++kt) {
        int kus = kt * 32 + ((l >> 4) << 3);
        int addr = arow * 128 + (kus ^ ((arow & 7) << 3));
        bf16x8 av = *reinterpret_cast<const bf16x8*>(&Albs[addr]);
#pragma unroll
        for (int nt = 0; nt < 4; ++nt)
            acc[nt] = __builtin_amdgcn_mfma_f32_16x16x32_bf16(av, bfrag[kt * 4 + nt], acc[nt], 0, 0, 0);
    }

    // epilogue: D row = (l>>4)*4+reg -> pair, col = l&15 (+16*nt) -> o
    const int ii = w >> 1;
    const int irow = i0 + ii;
#pragma unroll
    for (int nt = 0; nt < 4; ++nt) {
        int o = nt * 16 + (l & 15);
        float vm = -1e9f;
#pragma unroll
        for (int r = 0; r < 4; ++r) {
            int jj = ((w & 1) << 4) + ((l >> 4) << 2) + r;
            float s = acc[nt][r] + gl[jj][o];
            if (j0 + jj >= irow) vm = fmaxf(vm, s);
        }
        vm = fmaxf(vm, __shfl_xor(vm, 16));
        vm = fmaxf(vm, __shfl_xor(vm, 32));
        if (l < 16) part[w][o] = vm;
    }
    __syncthreads();

    if (tid < 128) {
        int ii2 = tid >> 6, o = tid & 63;
        float m = fmaxf(part[ii2 * 2][o], part[ii2 * 2 + 1][o]);
        float h = 1.0f / (1.0f + __expf(-m));     // sigmoid(max) == max(sigmoid): monotone
        atomicMax((int*)out + (((b * T_ + i0 + ii2) << 6) + o), __float_as_int(h));
    }
}

// ---------------------------------------------------------------------------
extern "C" void kernel_launch(void* const* d_in, const int* in_sizes, int n_in,
                              void* d_out, int out_size, void* d_ws, size_t ws_size,
                              hipStream_t stream) {
    const float* f  = (const float*)d_in[0];
    const float* W0 = (const float*)d_in[1];
    const float* b0 = (const float*)d_in[2];
    const float* W1 = (const float*)d_in[3];
    const float* b1 = (const float*)d_in[4];
    const float* W2 = (const float*)d_in[5];
    const float* b2 = (const float*)d_in[6];
    float* outp = (float*)d_out;

    // workspace layout
    char* ws = (char*)d_ws;
    unsigned short* tabmax = (unsigned short*)ws;                 // 10*B*T*64 bf16
    unsigned short* tabmin = tabmax + 10 * B_ * T_ * 64;          // 10*B*T*64 bf16
    unsigned short* wf     = tabmin + 10 * B_ * T_ * 64;          // 3*16*64*8 bf16
    float* cur0 = (float*)(wf + 3 * 16 * 64 * 8);                 // [B,T,128]
    float* gbuf = cur0 + B_ * T_ * 128;                           // [B,T,64]
    float* cur1 = gbuf + B_ * T_ * 64;                            // [B,T,64]
    float* cur2 = cur1 + B_ * T_ * 64;                            // [B,T,64]

    table_kernel<<<dim3(4, B_), dim3(512), 0, stream>>>(f, tabmax, tabmin);
    suffix_kernel<<<dim3(64, B_), dim3(512), 0, stream>>>(f, cur0);
    wfrag_kernel<<<dim3(16, 3), dim3(64), 0, stream>>>(W0, W1, W2, wf);

    const dim3 pgrid(16, 256, B_);

    g_kernel<128><<<dim3(B_ * T_ / 4), dim3(256), 0, stream>>>(cur0, W0, b0, gbuf, cur1);
    pair_kernel<<<pgrid, dim3(256), 0, stream>>>(tabmax, tabmin, wf + 0 * 8192, gbuf, cur1);

    g_kernel<64><<<dim3(B_ * T_ / 4), dim3(256), 0, stream>>>(cur1, W1, b1, gbuf, cur2);
    pair_kernel<<<pgrid, dim3(256), 0, stream>>>(tabmax, tabmin, wf + 1 * 8192, gbuf, cur2);

    g_kernel<64><<<dim3(B_ * T_ / 4), dim3(256), 0, stream>>>(cur2, W2, b2, gbuf, outp);
    pair_kernel<<<pgrid, dim3(256), 0, stream>>>(tabmax, tabmin, wf + 2 * 8192, gbuf, outp);
}

// Round 3
// 155.484 us; speedup vs baseline: 5.6812x; 2.1922x over previous
//
#include <hip/hip_runtime.h>
#include <hip/hip_bf16.h>
#include <math.h>

#define B_ 2
#define T_ 512
#define D_ 64

typedef __attribute__((ext_vector_type(8))) short bf16x8;
typedef __attribute__((ext_vector_type(8))) unsigned short u16x8;
typedef __attribute__((ext_vector_type(4))) float f32x4;

static __device__ __forceinline__ unsigned short f2bf(float v) {
    __hip_bfloat16 h = __float2bfloat16(v);
    return *reinterpret_cast<unsigned short*>(&h);
}
static __device__ __forceinline__ float bf2f(unsigned short u) {
    return __uint_as_float(((unsigned)u) << 16);
}

// ---------------------------------------------------------------------------
// Sparse tables (bf16): tab[k][b][t][c] = max/min of f[b, t .. t+2^k-1, c]
// Levels 0..9.  Running level kept in REGISTERS (16 ch/thread); neighbor
// t + 2^(k-1) fetched via LDS each level — no dependent global reads.
// ---------------------------------------------------------------------------
__global__ __launch_bounds__(512) void table_kernel(const float* __restrict__ f,
                                                    unsigned short* __restrict__ tmax,
                                                    unsigned short* __restrict__ tmin) {
    const int b = blockIdx.y;
    const int c0 = blockIdx.x * 16;
    const int t = threadIdx.x;

    __shared__ unsigned short lmax[512][16];
    __shared__ unsigned short lmin[512][16];

    u16x8 mx[2], mn[2];
#pragma unroll
    for (int h = 0; h < 2; ++h) {
        const float* fp = &f[((size_t)(b * T_ + t) << 6) + c0 + h * 8];
#pragma unroll
        for (int e = 0; e < 8; ++e) {
            unsigned short u = f2bf(fp[e]);
            mx[h][e] = u;
            mn[h][e] = u;
        }
        size_t base = ((size_t)(b * T_ + t) << 6) + c0 + h * 8;
        *reinterpret_cast<u16x8*>(&tmax[base]) = mx[h];
        *reinterpret_cast<u16x8*>(&tmin[base]) = mn[h];
    }

    for (int k = 1; k <= 9; ++k) {
        // publish level k-1 to LDS
        *reinterpret_cast<u16x8*>(&lmax[t][0]) = mx[0];
        *reinterpret_cast<u16x8*>(&lmax[t][8]) = mx[1];
        *reinterpret_cast<u16x8*>(&lmin[t][0]) = mn[0];
        *reinterpret_cast<u16x8*>(&lmin[t][8]) = mn[1];
        __syncthreads();

        int t2 = t + (1 << (k - 1));
        if (t2 > T_ - 1) t2 = T_ - 1;
        u16x8 qx0 = *reinterpret_cast<const u16x8*>(&lmax[t2][0]);
        u16x8 qx1 = *reinterpret_cast<const u16x8*>(&lmax[t2][8]);
        u16x8 qn0 = *reinterpret_cast<const u16x8*>(&lmin[t2][0]);
        u16x8 qn1 = *reinterpret_cast<const u16x8*>(&lmin[t2][8]);

#pragma unroll
        for (int e = 0; e < 8; ++e) {
            if (bf2f(qx0[e]) > bf2f(mx[0][e])) mx[0][e] = qx0[e];
            if (bf2f(qx1[e]) > bf2f(mx[1][e])) mx[1][e] = qx1[e];
            if (bf2f(qn0[e]) < bf2f(mn[0][e])) mn[0][e] = qn0[e];
            if (bf2f(qn1[e]) < bf2f(mn[1][e])) mn[1][e] = qn1[e];
        }

        size_t base = ((size_t)((k * B_ + b) * T_ + t) << 6) + c0;
        *reinterpret_cast<u16x8*>(&tmax[base]) = mx[0];
        *reinterpret_cast<u16x8*>(&tmax[base + 8]) = mx[1];
        *reinterpret_cast<u16x8*>(&tmin[base]) = mn[0];
        *reinterpret_cast<u16x8*>(&tmin[base + 8]) = mn[1];

        __syncthreads();   // protect LDS before next level overwrites
    }
}

// ---------------------------------------------------------------------------
// Suffix pools (fp32): cur0[b,t,:] = [max f[b,t..T-1], min f[b,t..T-1]]
// Hillis-Steele suffix scan in LDS, one block per (channel, b).
// ---------------------------------------------------------------------------
__global__ __launch_bounds__(512) void suffix_kernel(const float* __restrict__ f,
                                                     float* __restrict__ cur0) {
    const int c = blockIdx.x, b = blockIdx.y;
    const int t = threadIdx.x;
    __shared__ float smax[512];
    __shared__ float smin[512];
    float v = f[((b * T_ + t) << 6) + c];
    smax[t] = v; smin[t] = v;
    __syncthreads();
    for (int off = 1; off < 512; off <<= 1) {
        float a = (t + off < 512) ? smax[t + off] : -1e30f;
        float m = (t + off < 512) ? smin[t + off] : 1e30f;
        __syncthreads();
        smax[t] = fmaxf(smax[t], a);
        smin[t] = fminf(smin[t], m);
        __syncthreads();
    }
    cur0[((b * T_ + t) << 7) + c] = smax[t];
    cur0[((b * T_ + t) << 7) + 64 + c] = smin[t];
}

// ---------------------------------------------------------------------------
// Pre-pack W[C : C+128][64] into MFMA B-fragment order (bf16):
// wf[layer][frag=kt*4+nt][lane][e] = W[C + kt*32 + (lane>>4)*8 + e][nt*16 + (lane&15)]
// ---------------------------------------------------------------------------
__global__ void wfrag_kernel(const float* __restrict__ W0, const float* __restrict__ W1,
                             const float* __restrict__ W2, unsigned short* __restrict__ wf) {
    const int layer = blockIdx.y;
    const int fr = blockIdx.x;      // kt*4+nt
    const int l = threadIdx.x;      // 64
    const float* W = (layer == 0) ? W0 : ((layer == 1) ? W1 : W2);
    const int Coff = (layer == 0) ? 128 : 64;
    const int kt = fr >> 2, nt = fr & 3;
#pragma unroll
    for (int e = 0; e < 8; ++e) {
        int row = Coff + kt * 32 + ((l >> 4) << 3) + e;
        int col = nt * 16 + (l & 15);
        wf[((layer * 16 + fr) * 64 + l) * 8 + e] = f2bf(W[row * 64 + col]);
    }
}

// ---------------------------------------------------------------------------
// g[b,t,o] = bias[o] + sum_c cur[b,t,c] * W[c][o];   also zeroes next out buf.
// ---------------------------------------------------------------------------
template <int C>
__global__ __launch_bounds__(256) void g_kernel(const float* __restrict__ cur,
                                                const float* __restrict__ W,
                                                const float* __restrict__ bias,
                                                float* __restrict__ g,
                                                float* __restrict__ outz) {
    const int bt = blockIdx.x * 4 + (threadIdx.x >> 6);   // 0..B*T-1
    const int o = threadIdx.x & 63;
    float s = bias[o];
    const float* cp = &cur[(size_t)bt * C];
#pragma unroll 8
    for (int c = 0; c < C; ++c)
        s = fmaf(cp[c], W[c * 64 + o], s);
    g[(bt << 6) + o] = s;
    outz[(bt << 6) + o] = 0.0f;
}

// ---------------------------------------------------------------------------
// Pair GEMM: block = (b, 2 i's, 32 j's) = 64 pairs x K=128 x N=64 outputs.
//   A[pair][k] = [rmax(i,j) 64ch | rmin(i,j) 64ch] from sparse tables (bf16)
//   s = A·Wr + g[b,j,:];  out[b,i,o] = atomicMax over sigmoid(max_j s)
// A staged in XOR-swizzled LDS; W pre-packed fragment-order in global.
// ---------------------------------------------------------------------------
__global__ __launch_bounds__(256) void pair_kernel(const unsigned short* __restrict__ tabmax,
                                                   const unsigned short* __restrict__ tabmin,
                                                   const unsigned short* __restrict__ wf,
                                                   const float* __restrict__ g,
                                                   float* __restrict__ out) {
    const int jt = blockIdx.x, it = blockIdx.y, b = blockIdx.z;
    const int i0 = it * 2, j0 = jt * 32;
    if (j0 + 31 < i0) return;   // tile entirely below diagonal

    const int tid = threadIdx.x;
    const int l = tid & 63, w = tid >> 6;

    __shared__ unsigned short Albs[64 * 128];   // [pair][128ch], XOR-swizzled
    __shared__ float gl[32][65];
    __shared__ float part[4][64];

    // B fragments: 16 x dwordx4 per lane, identical across waves (L1 hit)
    bf16x8 bfrag[16];
#pragma unroll
    for (int q = 0; q < 16; ++q)
        bfrag[q] = *reinterpret_cast<const bf16x8*>(&wf[(q * 64 + l) * 8]);

    // stage g tile [32 j][64 o]
#pragma unroll
    for (int q = 0; q < 8; ++q) {
        int x = q * 256 + tid;
        gl[x >> 6][x & 63] = g[(size_t)((b * T_ + j0) << 6) + x];
    }

    // build A tile: 64 pairs x 16 chunks of 8 channels
#pragma unroll
    for (int q = 0; q < 4; ++q) {
        int item = q * 256 + tid;            // 0..1023
        int p = item >> 4, c8 = item & 15;
        int pi = i0 + (p >> 5);
        int pj = j0 + (p & 31);
        int je = pj < pi ? pi : pj;          // clamp below-diagonal (masked later)
        int len = je - pi + 1;
        int k = 31 - __clz(len);
        int t2 = je + 1 - (1 << k);
        const unsigned short* tab = (c8 < 8) ? tabmax : tabmin;
        int cc = (c8 & 7) * 8;
        u16x8 va = *reinterpret_cast<const u16x8*>(&tab[(((k * B_ + b) * T_ + pi) << 6) + cc]);
        u16x8 vb = *reinterpret_cast<const u16x8*>(&tab[(((k * B_ + b) * T_ + t2) << 6) + cc]);
        u16x8 r;
#pragma unroll
        for (int e = 0; e < 8; ++e) {
            float fa = bf2f(va[e]), fb = bf2f(vb[e]);
            bool pick_a = (c8 < 8) ? (fa >= fb) : (fa <= fb);
            r[e] = pick_a ? va[e] : vb[e];
        }
        int addr = p * 128 + ((c8 * 8) ^ ((p & 7) << 3));   // ushort units
        *reinterpret_cast<u16x8*>(&Albs[addr]) = r;
    }
    __syncthreads();

    // GEMM: wave w owns pair strip [w*16, w*16+16)
    f32x4 acc[4];
#pragma unroll
    for (int nt = 0; nt < 4; ++nt) acc[nt] = (f32x4){0.f, 0.f, 0.f, 0.f};
    const int arow = w * 16 + (l & 15);
#pragma unroll
    for (int kt = 0; kt < 4; ++kt) {
        int kus = kt * 32 + ((l >> 4) << 3);
        int addr = arow * 128 + (kus ^ ((arow & 7) << 3));
        bf16x8 av = *reinterpret_cast<const bf16x8*>(&Albs[addr]);
#pragma unroll
        for (int nt = 0; nt < 4; ++nt)
            acc[nt] = __builtin_amdgcn_mfma_f32_16x16x32_bf16(av, bfrag[kt * 4 + nt], acc[nt], 0, 0, 0);
    }

    // epilogue: D row = (l>>4)*4+reg -> pair, col = l&15 (+16*nt) -> o
    const int ii = w >> 1;
    const int irow = i0 + ii;
#pragma unroll
    for (int nt = 0; nt < 4; ++nt) {
        int o = nt * 16 + (l & 15);
        float vm = -1e9f;
#pragma unroll
        for (int r = 0; r < 4; ++r) {
            int jj = ((w & 1) << 4) + ((l >> 4) << 2) + r;
            float s = acc[nt][r] + gl[jj][o];
            if (j0 + jj >= irow) vm = fmaxf(vm, s);
        }
        vm = fmaxf(vm, __shfl_xor(vm, 16));
        vm = fmaxf(vm, __shfl_xor(vm, 32));
        if (l < 16) part[w][o] = vm;
    }
    __syncthreads();

    if (tid < 128) {
        int ii2 = tid >> 6, o = tid & 63;
        float m = fmaxf(part[ii2 * 2][o], part[ii2 * 2 + 1][o]);
        float h = 1.0f / (1.0f + __expf(-m));     // sigmoid(max) == max(sigmoid): monotone
        atomicMax((int*)out + (((b * T_ + i0 + ii2) << 6) + o), __float_as_int(h));
    }
}

// ---------------------------------------------------------------------------
extern "C" void kernel_launch(void* const* d_in, const int* in_sizes, int n_in,
                              void* d_out, int out_size, void* d_ws, size_t ws_size,
                              hipStream_t stream) {
    const float* f  = (const float*)d_in[0];
    const float* W0 = (const float*)d_in[1];
    const float* b0 = (const float*)d_in[2];
    const float* W1 = (const float*)d_in[3];
    const float* b1 = (const float*)d_in[4];
    const float* W2 = (const float*)d_in[5];
    const float* b2 = (const float*)d_in[6];
    float* outp = (float*)d_out;

    // workspace layout
    char* ws = (char*)d_ws;
    unsigned short* tabmax = (unsigned short*)ws;                 // 10*B*T*64 bf16
    unsigned short* tabmin = tabmax + 10 * B_ * T_ * 64;          // 10*B*T*64 bf16
    unsigned short* wf     = tabmin + 10 * B_ * T_ * 64;          // 3*16*64*8 bf16
    float* cur0 = (float*)(wf + 3 * 16 * 64 * 8);                 // [B,T,128]
    float* gbuf = cur0 + B_ * T_ * 128;                           // [B,T,64]
    float* cur1 = gbuf + B_ * T_ * 64;                            // [B,T,64]
    float* cur2 = cur1 + B_ * T_ * 64;                            // [B,T,64]

    table_kernel<<<dim3(4, B_), dim3(512), 0, stream>>>(f, tabmax, tabmin);
    suffix_kernel<<<dim3(64, B_), dim3(512), 0, stream>>>(f, cur0);
    wfrag_kernel<<<dim3(16, 3), dim3(64), 0, stream>>>(W0, W1, W2, wf);

    const dim3 pgrid(16, 256, B_);

    g_kernel<128><<<dim3(B_ * T_ / 4), dim3(256), 0, stream>>>(cur0, W0, b0, gbuf, cur1);
    pair_kernel<<<pgrid, dim3(256), 0, stream>>>(tabmax, tabmin, wf + 0 * 8192, gbuf, cur1);

    g_kernel<64><<<dim3(B_ * T_ / 4), dim3(256), 0, stream>>>(cur1, W1, b1, gbuf, cur2);
    pair_kernel<<<pgrid, dim3(256), 0, stream>>>(tabmax, tabmin, wf + 1 * 8192, gbuf, cur2);

    g_kernel<64><<<dim3(B_ * T_ / 4), dim3(256), 0, stream>>>(cur2, W2, b2, gbuf, outp);
    pair_kernel<<<pgrid, dim3(256), 0, stream>>>(tabmax, tabmin, wf + 2 * 8192, gbuf, outp);
}

// Round 4
// 106.415 us; speedup vs baseline: 8.3009x; 1.4611x over previous
//
#include <hip/hip_runtime.h>
#include <hip/hip_bf16.h>
#include <math.h>

#define B_ 2
#define T_ 512
#define D_ 64
#define NBLK_PER_B 2176   // sum_{jt=0..15} (16*jt+16)

typedef __attribute__((ext_vector_type(8))) short bf16x8;
typedef __attribute__((ext_vector_type(8))) unsigned short u16x8;
typedef __attribute__((ext_vector_type(4))) float f32x4;

static __device__ __forceinline__ unsigned short f2bf(float v) {
    __hip_bfloat16 h = __float2bfloat16(v);
    return *reinterpret_cast<unsigned short*>(&h);
}
static __device__ __forceinline__ float bf2f(unsigned short u) {
    return __uint_as_float(((unsigned)u) << 16);
}
static __device__ __forceinline__ unsigned short maxbits(unsigned short a, unsigned short b) {
    float m = fmaxf(bf2f(a), bf2f(b));
    return (unsigned short)(__float_as_uint(m) >> 16);   // exact: both are exact bf16
}
static __device__ __forceinline__ unsigned short minbits(unsigned short a, unsigned short b) {
    float m = fminf(bf2f(a), bf2f(b));
    return (unsigned short)(__float_as_uint(m) >> 16);
}

// ---------------------------------------------------------------------------
// Sparse tables (bf16): tab[k][b][t][c] = max/min of f[b, t .. t+2^k-1, c]
// Running level in registers; neighbor via LDS (no dependent global reads).
// ---------------------------------------------------------------------------
__global__ __launch_bounds__(512) void table_kernel(const float* __restrict__ f,
                                                    unsigned short* __restrict__ tmax,
                                                    unsigned short* __restrict__ tmin) {
    const int b = blockIdx.y;
    const int c0 = blockIdx.x * 16;
    const int t = threadIdx.x;

    __shared__ unsigned short lmax[512][16];
    __shared__ unsigned short lmin[512][16];

    u16x8 mx[2], mn[2];
#pragma unroll
    for (int h = 0; h < 2; ++h) {
        const float* fp = &f[((size_t)(b * T_ + t) << 6) + c0 + h * 8];
#pragma unroll
        for (int e = 0; e < 8; ++e) {
            unsigned short u = f2bf(fp[e]);
            mx[h][e] = u;
            mn[h][e] = u;
        }
        size_t base = ((size_t)(b * T_ + t) << 6) + c0 + h * 8;
        *reinterpret_cast<u16x8*>(&tmax[base]) = mx[h];
        *reinterpret_cast<u16x8*>(&tmin[base]) = mn[h];
    }

    for (int k = 1; k <= 9; ++k) {
        *reinterpret_cast<u16x8*>(&lmax[t][0]) = mx[0];
        *reinterpret_cast<u16x8*>(&lmax[t][8]) = mx[1];
        *reinterpret_cast<u16x8*>(&lmin[t][0]) = mn[0];
        *reinterpret_cast<u16x8*>(&lmin[t][8]) = mn[1];
        __syncthreads();

        int t2 = t + (1 << (k - 1));
        if (t2 > T_ - 1) t2 = T_ - 1;
        u16x8 qx0 = *reinterpret_cast<const u16x8*>(&lmax[t2][0]);
        u16x8 qx1 = *reinterpret_cast<const u16x8*>(&lmax[t2][8]);
        u16x8 qn0 = *reinterpret_cast<const u16x8*>(&lmin[t2][0]);
        u16x8 qn1 = *reinterpret_cast<const u16x8*>(&lmin[t2][8]);

#pragma unroll
        for (int e = 0; e < 8; ++e) {
            if (bf2f(qx0[e]) > bf2f(mx[0][e])) mx[0][e] = qx0[e];
            if (bf2f(qx1[e]) > bf2f(mx[1][e])) mx[1][e] = qx1[e];
            if (bf2f(qn0[e]) < bf2f(mn[0][e])) mn[0][e] = qn0[e];
            if (bf2f(qn1[e]) < bf2f(mn[1][e])) mn[1][e] = qn1[e];
        }

        size_t base = ((size_t)((k * B_ + b) * T_ + t) << 6) + c0;
        *reinterpret_cast<u16x8*>(&tmax[base]) = mx[0];
        *reinterpret_cast<u16x8*>(&tmax[base + 8]) = mx[1];
        *reinterpret_cast<u16x8*>(&tmin[base]) = mn[0];
        *reinterpret_cast<u16x8*>(&tmin[base + 8]) = mn[1];

        __syncthreads();
    }
}

// ---------------------------------------------------------------------------
// Intra-tile running pools (bf16): intra[b][jt][jj][c] =
//   running max (c<64) / min (c>=64) of f[b, jt*32 .. jt*32+jj, c&63]
// ---------------------------------------------------------------------------
__global__ __launch_bounds__(128) void intra_kernel(const float* __restrict__ f,
                                                    unsigned short* __restrict__ intra) {
    const int jt = blockIdx.x, b = blockIdx.y;
    const int c = threadIdx.x;          // 0..127
    const int ch = c & 63;
    const bool ismin = c >= 64;
    const int j0 = jt * 32;
    float run = bf2f(f2bf(f[((size_t)(b * T_ + j0) << 6) + ch]));
    intra[(size_t)(((b * 16 + jt) * 32) << 7) + c] = f2bf(run);
    for (int jj = 1; jj < 32; ++jj) {
        float v = bf2f(f2bf(f[((size_t)(b * T_ + j0 + jj) << 6) + ch]));
        run = ismin ? fminf(run, v) : fmaxf(run, v);
        intra[(size_t)(((b * 16 + jt) * 32 + jj) << 7) + c] = f2bf(run);
    }
}

// ---------------------------------------------------------------------------
// Suffix pools (fp32): cur0[b,t,:] = [max f[b,t..T-1], min f[b,t..T-1]]
// ---------------------------------------------------------------------------
__global__ __launch_bounds__(512) void suffix_kernel(const float* __restrict__ f,
                                                     float* __restrict__ cur0) {
    const int c = blockIdx.x, b = blockIdx.y;
    const int t = threadIdx.x;
    __shared__ float smax[512];
    __shared__ float smin[512];
    float v = f[((b * T_ + t) << 6) + c];
    smax[t] = v; smin[t] = v;
    __syncthreads();
    for (int off = 1; off < 512; off <<= 1) {
        float a = (t + off < 512) ? smax[t + off] : -1e30f;
        float m = (t + off < 512) ? smin[t + off] : 1e30f;
        __syncthreads();
        smax[t] = fmaxf(smax[t], a);
        smin[t] = fminf(smin[t], m);
        __syncthreads();
    }
    cur0[((b * T_ + t) << 7) + c] = smax[t];
    cur0[((b * T_ + t) << 7) + 64 + c] = smin[t];
}

// ---------------------------------------------------------------------------
// Pre-pack W[C : C+128][64] into MFMA B-fragment order (bf16).
// ---------------------------------------------------------------------------
__global__ void wfrag_kernel(const float* __restrict__ W0, const float* __restrict__ W1,
                             const float* __restrict__ W2, unsigned short* __restrict__ wf) {
    const int layer = blockIdx.y;
    const int fr = blockIdx.x;      // kt*4+nt
    const int l = threadIdx.x;      // 64
    const float* W = (layer == 0) ? W0 : ((layer == 1) ? W1 : W2);
    const int Coff = (layer == 0) ? 128 : 64;
    const int kt = fr >> 2, nt = fr & 3;
#pragma unroll
    for (int e = 0; e < 8; ++e) {
        int row = Coff + kt * 32 + ((l >> 4) << 3) + e;
        int col = nt * 16 + (l & 15);
        wf[((layer * 16 + fr) * 64 + l) * 8 + e] = f2bf(W[row * 64 + col]);
    }
}

// ---------------------------------------------------------------------------
// g[b,t,o] = bias[o] + sum_c cur[b,t,c] * W[c][o];   also zeroes next out buf.
// ---------------------------------------------------------------------------
template <int C>
__global__ __launch_bounds__(256) void g_kernel(const float* __restrict__ cur,
                                                const float* __restrict__ W,
                                                const float* __restrict__ bias,
                                                float* __restrict__ g,
                                                float* __restrict__ outz) {
    const int bt = blockIdx.x * 4 + (threadIdx.x >> 6);
    const int o = threadIdx.x & 63;
    float s = bias[o];
    const float* cp = &cur[(size_t)bt * C];
#pragma unroll 8
    for (int c = 0; c < C; ++c)
        s = fmaf(cp[c], W[c * 64 + o], s);
    g[(bt << 6) + o] = s;
    outz[(bt << 6) + o] = 0.0f;
}

// ---------------------------------------------------------------------------
// Pair GEMM over triangular tiles.  Block = (b, 2 i's, 32 j's).
// Non-diagonal (i0 < j0): A[p][c] = max/min(prefix[i][c], intra[j][c]) built
// directly into MFMA fragments from LDS (2 sparse queries/block total).
// Diagonal (i0 >= j0): per-lane sparse query (fragment chunk == one query).
// ---------------------------------------------------------------------------
__global__ __launch_bounds__(256) void pair_kernel(const unsigned short* __restrict__ tabmax,
                                                   const unsigned short* __restrict__ tabmin,
                                                   const unsigned short* __restrict__ intra,
                                                   const unsigned short* __restrict__ wf,
                                                   const float* __restrict__ g,
                                                   float* __restrict__ out) {
    // decode triangular block id -> (b, jt, it)
    int m = blockIdx.x;
    int b = 0;
    if (m >= NBLK_PER_B) { b = 1; m -= NBLK_PER_B; }
    int jt = 0;
    while (m >= 8 * (jt + 1) * (jt + 2)) ++jt;        // <=15 scalar iters
    const int it = m - 8 * jt * (jt + 1);             // 0 .. 16*jt+15
    const bool diag = (it >= 16 * jt);
    const int i0 = it * 2, j0 = jt * 32;

    const int tid = threadIdx.x;
    const int l = tid & 63, w = tid >> 6;

    __shared__ unsigned short intr[32][136];   // +8 u16 pad: breaks 256B-stride conflicts
    __shared__ unsigned short pref[2][136];
    __shared__ float gl[32][68];
    __shared__ float part[4][64];

    // B fragments (same addresses for all waves/blocks -> L1 hot)
    bf16x8 bfrag[16];
#pragma unroll
    for (int q = 0; q < 16; ++q)
        bfrag[q] = *reinterpret_cast<const bf16x8*>(&wf[(q * 64 + l) * 8]);

    // stage g tile [32 j][64 o] (vectorized)
    {
        const float4* gp = (const float4*)&g[(size_t)((b * T_ + j0) << 6)];
#pragma unroll
        for (int q = 0; q < 2; ++q) {
            int idx = q * 256 + tid;            // float4 index
            float4 v = gp[idx];
            int e0 = idx * 4;
            *reinterpret_cast<float4*>(&gl[e0 >> 6][e0 & 63]) = v;
        }
    }

    if (!diag) {
        // stage intra tile (8 KB)
#pragma unroll
        for (int q = 0; q < 2; ++q) {
            int chn = q * 256 + tid;            // 0..511 chunk index
            int jj = chn >> 4, c8 = chn & 15;
            u16x8 v = *reinterpret_cast<const u16x8*>(
                &intra[(size_t)(((b * 16 + jt) * 32 + jj) << 7) + c8 * 8]);
            *reinterpret_cast<u16x8*>(&intr[jj][c8 * 8]) = v;
        }
        // prefix queries: 2 i's x 16 chunks
        if (tid < 32) {
            const int isel = tid >> 4;
            const int c8 = tid & 15;
            const int i = i0 + isel;
            const int len = j0 - i;             // >= 1
            const int kk = 31 - __clz(len);
            const int t2 = j0 - (1 << kk);
            const unsigned short* tab = (c8 < 8) ? tabmax : tabmin;
            const int cc = (c8 & 7) * 8;
            u16x8 va = *reinterpret_cast<const u16x8*>(&tab[(((size_t)(kk * B_ + b) * T_ + i) << 6) + cc]);
            u16x8 vb = *reinterpret_cast<const u16x8*>(&tab[(((size_t)(kk * B_ + b) * T_ + t2) << 6) + cc]);
            u16x8 r;
#pragma unroll
            for (int e = 0; e < 8; ++e)
                r[e] = (c8 < 8) ? maxbits(va[e], vb[e]) : minbits(va[e], vb[e]);
            *reinterpret_cast<u16x8*>(&pref[isel][c8 * 8]) = r;
        }
    }
    __syncthreads();

    f32x4 acc[4];
#pragma unroll
    for (int nt = 0; nt < 4; ++nt) acc[nt] = (f32x4){0.f, 0.f, 0.f, 0.f};

    const int p = w * 16 + (l & 15);           // this lane's A-row (pair)
    const int pisel = p >> 5;                  // i index within block (0/1)
    const int pjj = p & 31;                    // j index within tile

    if (!diag) {
#pragma unroll
        for (int kt = 0; kt < 4; ++kt) {
            const int cbase = kt * 32 + ((l >> 4) << 3);
            u16x8 iv = *reinterpret_cast<const u16x8*>(&intr[pjj][cbase]);
            u16x8 pv = *reinterpret_cast<const u16x8*>(&pref[pisel][cbase]);
            bf16x8 av;
            if (kt < 2) {
#pragma unroll
                for (int e = 0; e < 8; ++e) av[e] = (short)maxbits(iv[e], pv[e]);
            } else {
#pragma unroll
                for (int e = 0; e < 8; ++e) av[e] = (short)minbits(iv[e], pv[e]);
            }
#pragma unroll
            for (int nt = 0; nt < 4; ++nt)
                acc[nt] = __builtin_amdgcn_mfma_f32_16x16x32_bf16(av, bfrag[kt * 4 + nt], acc[nt], 0, 0, 0);
        }
    } else {
        const int pi = i0 + pisel;
        const int pj = j0 + pjj;
        const int je = (pj < pi) ? pi : pj;    // clamp: masked in epilogue
        const int len = je - pi + 1;
        const int kk = 31 - __clz(len);
        const int t2 = je + 1 - (1 << kk);
#pragma unroll
        for (int kt = 0; kt < 4; ++kt) {
            const int c8 = kt * 4 + (l >> 4);
            const unsigned short* tab = (kt < 2) ? tabmax : tabmin;
            const int cc = (c8 & 7) * 8;
            u16x8 va = *reinterpret_cast<const u16x8*>(&tab[(((size_t)(kk * B_ + b) * T_ + pi) << 6) + cc]);
            u16x8 vb = *reinterpret_cast<const u16x8*>(&tab[(((size_t)(kk * B_ + b) * T_ + t2) << 6) + cc]);
            bf16x8 av;
            if (kt < 2) {
#pragma unroll
                for (int e = 0; e < 8; ++e) av[e] = (short)maxbits(va[e], vb[e]);
            } else {
#pragma unroll
                for (int e = 0; e < 8; ++e) av[e] = (short)minbits(va[e], vb[e]);
            }
#pragma unroll
            for (int nt = 0; nt < 4; ++nt)
                acc[nt] = __builtin_amdgcn_mfma_f32_16x16x32_bf16(av, bfrag[kt * 4 + nt], acc[nt], 0, 0, 0);
        }
    }

    // epilogue: D row=(l>>4)*4+r -> pair, col=l&15 (+16*nt) -> o
    const int ii = w >> 1;
    const int irow = i0 + ii;
#pragma unroll
    for (int nt = 0; nt < 4; ++nt) {
        int o = nt * 16 + (l & 15);
        float vm = -1e9f;
#pragma unroll
        for (int r = 0; r < 4; ++r) {
            int jj = ((w & 1) << 4) + ((l >> 4) << 2) + r;
            float s = acc[nt][r] + gl[jj][o];
            if (j0 + jj >= irow) vm = fmaxf(vm, s);
        }
        vm = fmaxf(vm, __shfl_xor(vm, 16));
        vm = fmaxf(vm, __shfl_xor(vm, 32));
        if (l < 16) part[w][o] = vm;
    }
    __syncthreads();

    if (tid < 128) {
        int ii2 = tid >> 6, o = tid & 63;
        float m2 = fmaxf(part[ii2 * 2][o], part[ii2 * 2 + 1][o]);
        float h = 1.0f / (1.0f + __expf(-m2));   // sigmoid(max) == max(sigmoid)
        atomicMax((int*)out + (((b * T_ + i0 + ii2) << 6) + o), __float_as_int(h));
    }
}

// ---------------------------------------------------------------------------
extern "C" void kernel_launch(void* const* d_in, const int* in_sizes, int n_in,
                              void* d_out, int out_size, void* d_ws, size_t ws_size,
                              hipStream_t stream) {
    const float* f  = (const float*)d_in[0];
    const float* W0 = (const float*)d_in[1];
    const float* b0 = (const float*)d_in[2];
    const float* W1 = (const float*)d_in[3];
    const float* b1 = (const float*)d_in[4];
    const float* W2 = (const float*)d_in[5];
    const float* b2 = (const float*)d_in[6];
    float* outp = (float*)d_out;

    // workspace layout
    char* ws = (char*)d_ws;
    unsigned short* tabmax = (unsigned short*)ws;                 // 10*B*T*64
    unsigned short* tabmin = tabmax + 10 * B_ * T_ * 64;          // 10*B*T*64
    unsigned short* wf     = tabmin + 10 * B_ * T_ * 64;          // 3*16*64*8
    unsigned short* intra  = wf + 3 * 16 * 64 * 8;                // B*16*32*128
    float* cur0 = (float*)(intra + B_ * 16 * 32 * 128);           // [B,T,128]
    float* gbuf = cur0 + B_ * T_ * 128;                           // [B,T,64]
    float* cur1 = gbuf + B_ * T_ * 64;                            // [B,T,64]
    float* cur2 = cur1 + B_ * T_ * 64;                            // [B,T,64]

    table_kernel<<<dim3(4, B_), dim3(512), 0, stream>>>(f, tabmax, tabmin);
    intra_kernel<<<dim3(16, B_), dim3(128), 0, stream>>>(f, intra);
    suffix_kernel<<<dim3(64, B_), dim3(512), 0, stream>>>(f, cur0);
    wfrag_kernel<<<dim3(16, 3), dim3(64), 0, stream>>>(W0, W1, W2, wf);

    const dim3 pgrid(B_ * NBLK_PER_B);

    g_kernel<128><<<dim3(B_ * T_ / 4), dim3(256), 0, stream>>>(cur0, W0, b0, gbuf, cur1);
    pair_kernel<<<pgrid, dim3(256), 0, stream>>>(tabmax, tabmin, intra, wf + 0 * 8192, gbuf, cur1);

    g_kernel<64><<<dim3(B_ * T_ / 4), dim3(256), 0, stream>>>(cur1, W1, b1, gbuf, cur2);
    pair_kernel<<<pgrid, dim3(256), 0, stream>>>(tabmax, tabmin, intra, wf + 1 * 8192, gbuf, cur2);

    g_kernel<64><<<dim3(B_ * T_ / 4), dim3(256), 0, stream>>>(cur2, W2, b2, gbuf, outp);
    pair_kernel<<<pgrid, dim3(256), 0, stream>>>(tabmax, tabmin, intra, wf + 2 * 8192, gbuf, outp);
}

// Round 5
// 85.955 us; speedup vs baseline: 10.2768x; 1.2380x over previous
//
#include <hip/hip_runtime.h>
#include <hip/hip_bf16.h>
#include <math.h>

#define B_ 2
#define T_ 512
#define D_ 64
#define NBLK_PER_B 1088   // sum_{jt=0..15} (8*jt+8)

typedef __attribute__((ext_vector_type(8))) short bf16x8;
typedef __attribute__((ext_vector_type(8))) unsigned short u16x8;
typedef __attribute__((ext_vector_type(4))) float f32x4;

static __device__ __forceinline__ unsigned short f2bf(float v) {
    __hip_bfloat16 h = __float2bfloat16(v);
    return *reinterpret_cast<unsigned short*>(&h);
}
static __device__ __forceinline__ float bf2f(unsigned short u) {
    return __uint_as_float(((unsigned)u) << 16);
}
static __device__ __forceinline__ unsigned short maxbits(unsigned short a, unsigned short b) {
    float m = fmaxf(bf2f(a), bf2f(b));
    return (unsigned short)(__float_as_uint(m) >> 16);
}
static __device__ __forceinline__ unsigned short minbits(unsigned short a, unsigned short b) {
    float m = fminf(bf2f(a), bf2f(b));
    return (unsigned short)(__float_as_uint(m) >> 16);
}

// ---------------------------------------------------------------------------
// Fused prep: [0,8) sparse tables | [8,11) W fragment pack | [11,107) zeroing.
// tab[k][b][t][c] = max/min of f[b, t..t+2^k-1, c], k=0..9, bf16.
// wf[layer][fr=kt*4+nt][lane][e] = W[kt*32+(lane>>4)*8+e][nt*16+(lane&15)], full K.
// ---------------------------------------------------------------------------
__global__ __launch_bounds__(512) void prep_kernel(
    const float* __restrict__ f,
    const float* __restrict__ W0, const float* __restrict__ W1, const float* __restrict__ W2,
    unsigned short* __restrict__ tmax, unsigned short* __restrict__ tmin,
    unsigned short* __restrict__ wf,
    float* __restrict__ z0, float* __restrict__ z1, float* __restrict__ z2) {

    __shared__ unsigned short lmax[512][16];
    __shared__ unsigned short lmin[512][16];

    const int blk = blockIdx.x;
    const int tid = threadIdx.x;

    if (blk < 8) {
        // ---- sparse tables ----
        const int b = blk & 1;
        const int c0 = (blk >> 1) * 16;
        const int t = tid;

        u16x8 mx[2], mn[2];
#pragma unroll
        for (int h = 0; h < 2; ++h) {
            const float* fp = &f[((size_t)(b * T_ + t) << 6) + c0 + h * 8];
#pragma unroll
            for (int e = 0; e < 8; ++e) {
                unsigned short u = f2bf(fp[e]);
                mx[h][e] = u; mn[h][e] = u;
            }
            size_t base = ((size_t)(b * T_ + t) << 6) + c0 + h * 8;
            *reinterpret_cast<u16x8*>(&tmax[base]) = mx[h];
            *reinterpret_cast<u16x8*>(&tmin[base]) = mn[h];
        }
        for (int k = 1; k <= 9; ++k) {
            *reinterpret_cast<u16x8*>(&lmax[t][0]) = mx[0];
            *reinterpret_cast<u16x8*>(&lmax[t][8]) = mx[1];
            *reinterpret_cast<u16x8*>(&lmin[t][0]) = mn[0];
            *reinterpret_cast<u16x8*>(&lmin[t][8]) = mn[1];
            __syncthreads();
            int t2 = t + (1 << (k - 1));
            if (t2 > T_ - 1) t2 = T_ - 1;
            u16x8 qx0 = *reinterpret_cast<const u16x8*>(&lmax[t2][0]);
            u16x8 qx1 = *reinterpret_cast<const u16x8*>(&lmax[t2][8]);
            u16x8 qn0 = *reinterpret_cast<const u16x8*>(&lmin[t2][0]);
            u16x8 qn1 = *reinterpret_cast<const u16x8*>(&lmin[t2][8]);
#pragma unroll
            for (int e = 0; e < 8; ++e) {
                mx[0][e] = maxbits(mx[0][e], qx0[e]);
                mx[1][e] = maxbits(mx[1][e], qx1[e]);
                mn[0][e] = minbits(mn[0][e], qn0[e]);
                mn[1][e] = minbits(mn[1][e], qn1[e]);
            }
            size_t base = ((size_t)((k * B_ + b) * T_ + t) << 6) + c0;
            *reinterpret_cast<u16x8*>(&tmax[base]) = mx[0];
            *reinterpret_cast<u16x8*>(&tmax[base + 8]) = mx[1];
            *reinterpret_cast<u16x8*>(&tmin[base]) = mn[0];
            *reinterpret_cast<u16x8*>(&tmin[base + 8]) = mn[1];
            __syncthreads();
        }
    } else if (blk < 11) {
        // ---- W fragment pack (full K) ----
        const int layer = blk - 8;
        const float* W = (layer == 0) ? W0 : ((layer == 1) ? W1 : W2);
        const int FRS = (layer == 0) ? 32 : 24;   // (K/32)*4
        const int l = tid & 63;
        for (int fr = tid >> 6; fr < FRS; fr += 8) {
            int kt = fr >> 2, nt = fr & 3;
#pragma unroll
            for (int e = 0; e < 8; ++e) {
                int row = kt * 32 + ((l >> 4) << 3) + e;
                int col = nt * 16 + (l & 15);
                wf[((size_t)(layer * 32 + fr) * 64 + l) * 8 + e] = f2bf(W[row * 64 + col]);
            }
        }
    } else {
        // ---- zero cur1 / cur2 / out ----
        int fi = (blk - 11) * 512 + tid;   // float4 index, 0..49151
        float4 z = {0.f, 0.f, 0.f, 0.f};
        if (fi < 16384)       reinterpret_cast<float4*>(z0)[fi] = z;
        else if (fi < 32768)  reinterpret_cast<float4*>(z1)[fi - 16384] = z;
        else                  reinterpret_cast<float4*>(z2)[fi - 32768] = z;
    }
}

// ---------------------------------------------------------------------------
// Pair GEMM over triangular tiles.  Block = (b, 4 i's, 32 j's), M=128 N=64.
// K = C + 128: A row p = [ cur(b, j) C ch | rangemax f[i..j] | rangemin ].
// Non-diag: r-part = combine(prefix[i] (4 queries), intra[j] via table queries).
// Diag: per-lane full-range table queries.  Wave w owns i = i0+w entirely:
// epilogue is wave-local (shfl reduce + sigmoid + atomicMax), bias in epilogue.
// ---------------------------------------------------------------------------
template <int C, bool FROM_TAB>
__global__ __launch_bounds__(256) void pair_kernel(
    const unsigned short* __restrict__ tabmax,
    const unsigned short* __restrict__ tabmin,
    const float* __restrict__ curprev,     // fp32 [B,T,64]; unused if FROM_TAB
    const unsigned short* __restrict__ wf, // layer base, fragment order
    const float* __restrict__ bias,
    float* __restrict__ out) {

    constexpr int KTC = C / 32;       // cur k-tiles (4 or 2)
    constexpr int KT = KTC + 4;       // total k-tiles
    constexpr int CP = (C == 128) ? 136 : 72;

    // decode triangular block id -> (b, jt, it)
    int m = blockIdx.x;
    int b = 0;
    if (m >= NBLK_PER_B) { b = 1; m -= NBLK_PER_B; }
    int jt = 0;
    while (m >= 4 * (jt + 1) * (jt + 2)) ++jt;
    const int it = m - 4 * jt * (jt + 1);      // 0 .. 8*jt+7
    const bool diag = (it >= 8 * jt);
    const int i0 = it * 4, j0 = jt * 32;

    const int tid = threadIdx.x;
    const int l = tid & 63, w = tid >> 6;
    const int lg = l >> 4, li = l & 15;

    __shared__ unsigned short curl[32][CP];
    __shared__ unsigned short intr[32][136];
    __shared__ unsigned short pref[4][136];

    // ---- stage cur tile [32 j][C ch] as bf16 ----
    if (FROM_TAB) {
        // cur0[b,t] = [suffix max | suffix min] = range query [t, T-1]
#pragma unroll
        for (int q = 0; q < 2; ++q) {
            int chn = q * 256 + tid;           // 0..511
            int jj = chn >> 4, c8 = chn & 15;
            int t = j0 + jj;
            int len = T_ - t;
            int kk = 31 - __clz(len);
            int t2 = T_ - (1 << kk);
            const unsigned short* tab = (c8 < 8) ? tabmax : tabmin;
            int cc = (c8 & 7) * 8;
            u16x8 va = *reinterpret_cast<const u16x8*>(&tab[(((size_t)(kk * B_ + b) * T_ + t) << 6) + cc]);
            u16x8 vb = *reinterpret_cast<const u16x8*>(&tab[(((size_t)(kk * B_ + b) * T_ + t2) << 6) + cc]);
            u16x8 r;
#pragma unroll
            for (int e = 0; e < 8; ++e)
                r[e] = (c8 < 8) ? maxbits(va[e], vb[e]) : minbits(va[e], vb[e]);
            *reinterpret_cast<u16x8*>(&curl[jj][c8 * 8]) = r;
        }
    } else {
        int jj = tid >> 3, c8 = tid & 7;       // 256 chunks
        const float* cp = &curprev[((size_t)(b * T_ + j0 + jj) << 6) + c8 * 8];
        float4 v0 = *reinterpret_cast<const float4*>(cp);
        float4 v1 = *reinterpret_cast<const float4*>(cp + 4);
        u16x8 r;
        r[0] = f2bf(v0.x); r[1] = f2bf(v0.y); r[2] = f2bf(v0.z); r[3] = f2bf(v0.w);
        r[4] = f2bf(v1.x); r[5] = f2bf(v1.y); r[6] = f2bf(v1.z); r[7] = f2bf(v1.w);
        *reinterpret_cast<u16x8*>(&curl[jj][c8 * 8]) = r;
    }

    if (!diag) {
        // ---- intra tile via table range queries [j0, j0+jj] ----
#pragma unroll
        for (int q = 0; q < 2; ++q) {
            int chn = q * 256 + tid;
            int jj = chn >> 4, c8 = chn & 15;
            int len = jj + 1;
            int kk = 31 - __clz(len);
            int t2 = j0 + jj + 1 - (1 << kk);
            const unsigned short* tab = (c8 < 8) ? tabmax : tabmin;
            int cc = (c8 & 7) * 8;
            u16x8 va = *reinterpret_cast<const u16x8*>(&tab[(((size_t)(kk * B_ + b) * T_ + j0) << 6) + cc]);
            u16x8 vb = *reinterpret_cast<const u16x8*>(&tab[(((size_t)(kk * B_ + b) * T_ + t2) << 6) + cc]);
            u16x8 r;
#pragma unroll
            for (int e = 0; e < 8; ++e)
                r[e] = (c8 < 8) ? maxbits(va[e], vb[e]) : minbits(va[e], vb[e]);
            *reinterpret_cast<u16x8*>(&intr[jj][c8 * 8]) = r;
        }
        // ---- prefix queries: 4 i's x 16 chunks, range [i, j0-1] ----
        if (tid < 64) {
            int isel = tid >> 4, c8 = tid & 15;
            int i = i0 + isel;
            int len = j0 - i;                  // >= 1 (non-diag)
            int kk = 31 - __clz(len);
            int t2 = j0 - (1 << kk);
            const unsigned short* tab = (c8 < 8) ? tabmax : tabmin;
            int cc = (c8 & 7) * 8;
            u16x8 va = *reinterpret_cast<const u16x8*>(&tab[(((size_t)(kk * B_ + b) * T_ + i) << 6) + cc]);
            u16x8 vb = *reinterpret_cast<const u16x8*>(&tab[(((size_t)(kk * B_ + b) * T_ + t2) << 6) + cc]);
            u16x8 r;
#pragma unroll
            for (int e = 0; e < 8; ++e)
                r[e] = (c8 < 8) ? maxbits(va[e], vb[e]) : minbits(va[e], vb[e]);
            *reinterpret_cast<u16x8*>(&pref[isel][c8 * 8]) = r;
        }
    }
    __syncthreads();

    // ---- GEMM: wave w -> i = i0+w, strips s=0,1 cover jj 0..31 ----
    f32x4 acc[2][4];
#pragma unroll
    for (int s = 0; s < 2; ++s)
#pragma unroll
        for (int nt = 0; nt < 4; ++nt) acc[s][nt] = (f32x4){0.f, 0.f, 0.f, 0.f};

    const int pi = i0 + w;

#pragma unroll
    for (int kt = 0; kt < KT; ++kt) {
        bf16x8 bfr[4];
#pragma unroll
        for (int nt = 0; nt < 4; ++nt)
            bfr[nt] = *reinterpret_cast<const bf16x8*>(&wf[(size_t)((kt * 4 + nt) * 64 + l) * 8]);

#pragma unroll
        for (int s = 0; s < 2; ++s) {
            const int pjj = 16 * s + li;
            bf16x8 av;
            if (kt < KTC) {
                av = *reinterpret_cast<const bf16x8*>(&curl[pjj][kt * 32 + lg * 8]);
            } else {
                const int krt = kt - KTC;
                const int c8 = krt * 4 + lg;
                if (!diag) {
                    u16x8 iv = *reinterpret_cast<const u16x8*>(&intr[pjj][c8 * 8]);
                    u16x8 pv = *reinterpret_cast<const u16x8*>(&pref[w][c8 * 8]);
#pragma unroll
                    for (int e = 0; e < 8; ++e)
                        av[e] = (short)((c8 < 8) ? maxbits(iv[e], pv[e]) : minbits(iv[e], pv[e]));
                } else {
                    const int pj = j0 + pjj;
                    const int je = (pj < pi) ? pi : pj;
                    const int len = je - pi + 1;
                    const int kk = 31 - __clz(len);
                    const int t2 = je + 1 - (1 << kk);
                    const unsigned short* tab = (c8 < 8) ? tabmax : tabmin;
                    const int cc = (c8 & 7) * 8;
                    u16x8 va = *reinterpret_cast<const u16x8*>(&tab[(((size_t)(kk * B_ + b) * T_ + pi) << 6) + cc]);
                    u16x8 vb = *reinterpret_cast<const u16x8*>(&tab[(((size_t)(kk * B_ + b) * T_ + t2) << 6) + cc]);
#pragma unroll
                    for (int e = 0; e < 8; ++e)
                        av[e] = (short)((c8 < 8) ? maxbits(va[e], vb[e]) : minbits(va[e], vb[e]));
                }
            }
#pragma unroll
            for (int nt = 0; nt < 4; ++nt)
                acc[s][nt] = __builtin_amdgcn_mfma_f32_16x16x32_bf16(av, bfr[nt], acc[s][nt], 0, 0, 0);
        }
    }

    // ---- epilogue: wave-local max over jj, +bias, sigmoid, atomicMax ----
#pragma unroll
    for (int nt = 0; nt < 4; ++nt) {
        float vm = -1e9f;
#pragma unroll
        for (int s = 0; s < 2; ++s)
#pragma unroll
            for (int r = 0; r < 4; ++r) {
                int jj = 16 * s + lg * 4 + r;   // D row -> jj
                if (j0 + jj >= pi) vm = fmaxf(vm, acc[s][nt][r]);
            }
        vm = fmaxf(vm, __shfl_xor(vm, 16));
        vm = fmaxf(vm, __shfl_xor(vm, 32));
        if (l < 16) {
            int o = nt * 16 + li;
            float h = 1.0f / (1.0f + __expf(-(vm + bias[o])));
            atomicMax((int*)out + (((size_t)(b * T_ + pi) << 6) + o), __float_as_int(h));
        }
    }
}

// ---------------------------------------------------------------------------
extern "C" void kernel_launch(void* const* d_in, const int* in_sizes, int n_in,
                              void* d_out, int out_size, void* d_ws, size_t ws_size,
                              hipStream_t stream) {
    const float* f  = (const float*)d_in[0];
    const float* W0 = (const float*)d_in[1];
    const float* b0 = (const float*)d_in[2];
    const float* W1 = (const float*)d_in[3];
    const float* b1 = (const float*)d_in[4];
    const float* W2 = (const float*)d_in[5];
    const float* b2 = (const float*)d_in[6];
    float* outp = (float*)d_out;

    // workspace layout
    unsigned short* tabmax = (unsigned short*)d_ws;               // 10*B*T*64
    unsigned short* tabmin = tabmax + 10 * B_ * T_ * 64;          // 10*B*T*64
    unsigned short* wf     = tabmin + 10 * B_ * T_ * 64;          // 3*32*64*8
    float* cur1 = (float*)(wf + 3 * 32 * 64 * 8);                 // [B,T,64]
    float* cur2 = cur1 + B_ * T_ * 64;                            // [B,T,64]

    prep_kernel<<<dim3(107), dim3(512), 0, stream>>>(f, W0, W1, W2,
                                                     tabmax, tabmin, wf,
                                                     cur1, cur2, outp);

    const dim3 pgrid(B_ * NBLK_PER_B);
    pair_kernel<128, true ><<<pgrid, dim3(256), 0, stream>>>(tabmax, tabmin, nullptr,
                                                             wf + 0 * 32 * 64 * 8, b0, cur1);
    pair_kernel<64,  false><<<pgrid, dim3(256), 0, stream>>>(tabmax, tabmin, cur1,
                                                             wf + 1 * 32 * 64 * 8, b1, cur2);
    pair_kernel<64,  false><<<pgrid, dim3(256), 0, stream>>>(tabmax, tabmin, cur2,
                                                             wf + 2 * 32 * 64 * 8, b2, outp);
}

// Round 6
// 83.530 us; speedup vs baseline: 10.5752x; 1.0290x over previous
//
#include <hip/hip_runtime.h>
#include <hip/hip_bf16.h>
#include <math.h>

#define B_ 2
#define T_ 512
#define D_ 64
#define NBLK_PER_B 1088   // sum_{jt=0..15} (8*jt+8)

typedef __attribute__((ext_vector_type(8))) short bf16x8;
typedef __attribute__((ext_vector_type(8))) unsigned short u16x8;
typedef __attribute__((ext_vector_type(4))) float f32x4;

static __device__ __forceinline__ unsigned short f2bf(float v) {
    __hip_bfloat16 h = __float2bfloat16(v);
    return *reinterpret_cast<unsigned short*>(&h);
}
static __device__ __forceinline__ float bf2f(unsigned short u) {
    return __uint_as_float(((unsigned)u) << 16);
}
static __device__ __forceinline__ unsigned short maxbits(unsigned short a, unsigned short b) {
    float m = fmaxf(bf2f(a), bf2f(b));
    return (unsigned short)(__float_as_uint(m) >> 16);
}
static __device__ __forceinline__ unsigned short minbits(unsigned short a, unsigned short b) {
    float m = fminf(bf2f(a), bf2f(b));
    return (unsigned short)(__float_as_uint(m) >> 16);
}

// ---------------------------------------------------------------------------
// Fused prep (267 heterogeneous blocks, 512 threads):
//  [0,8)    sparse tables tab[k][b][t][c], k=0..9, bf16
//  [8,11)   W fragment pack (full K)
//  [11,139) cur0bf[b][t][128] = bf16 suffix max/min of f (Hillis-Steele)
//  [139,171) intra[b][jt][jj][128] = running max/min within 32-j tile (scan)
//  [171,267) zero cur1 / cur2 / out
// ---------------------------------------------------------------------------
__global__ __launch_bounds__(512) void prep_kernel(
    const float* __restrict__ f,
    const float* __restrict__ W0, const float* __restrict__ W1, const float* __restrict__ W2,
    unsigned short* __restrict__ tmax, unsigned short* __restrict__ tmin,
    unsigned short* __restrict__ wf,
    unsigned short* __restrict__ cur0bf, unsigned short* __restrict__ intra,
    float* __restrict__ z0, float* __restrict__ z1, float* __restrict__ z2) {

    __shared__ unsigned short lmax[512][16];
    __shared__ unsigned short lmin[512][16];

    const int blk = blockIdx.x;
    const int tid = threadIdx.x;

    if (blk < 8) {
        // ---- sparse tables ----
        const int b = blk & 1;
        const int c0 = (blk >> 1) * 16;
        const int t = tid;

        u16x8 mx[2], mn[2];
#pragma unroll
        for (int h = 0; h < 2; ++h) {
            const float* fp = &f[((size_t)(b * T_ + t) << 6) + c0 + h * 8];
#pragma unroll
            for (int e = 0; e < 8; ++e) {
                unsigned short u = f2bf(fp[e]);
                mx[h][e] = u; mn[h][e] = u;
            }
            size_t base = ((size_t)(b * T_ + t) << 6) + c0 + h * 8;
            *reinterpret_cast<u16x8*>(&tmax[base]) = mx[h];
            *reinterpret_cast<u16x8*>(&tmin[base]) = mn[h];
        }
        for (int k = 1; k <= 9; ++k) {
            *reinterpret_cast<u16x8*>(&lmax[t][0]) = mx[0];
            *reinterpret_cast<u16x8*>(&lmax[t][8]) = mx[1];
            *reinterpret_cast<u16x8*>(&lmin[t][0]) = mn[0];
            *reinterpret_cast<u16x8*>(&lmin[t][8]) = mn[1];
            __syncthreads();
            int t2 = t + (1 << (k - 1));
            if (t2 > T_ - 1) t2 = T_ - 1;
            u16x8 qx0 = *reinterpret_cast<const u16x8*>(&lmax[t2][0]);
            u16x8 qx1 = *reinterpret_cast<const u16x8*>(&lmax[t2][8]);
            u16x8 qn0 = *reinterpret_cast<const u16x8*>(&lmin[t2][0]);
            u16x8 qn1 = *reinterpret_cast<const u16x8*>(&lmin[t2][8]);
#pragma unroll
            for (int e = 0; e < 8; ++e) {
                mx[0][e] = maxbits(mx[0][e], qx0[e]);
                mx[1][e] = maxbits(mx[1][e], qx1[e]);
                mn[0][e] = minbits(mn[0][e], qn0[e]);
                mn[1][e] = minbits(mn[1][e], qn1[e]);
            }
            size_t base = ((size_t)((k * B_ + b) * T_ + t) << 6) + c0;
            *reinterpret_cast<u16x8*>(&tmax[base]) = mx[0];
            *reinterpret_cast<u16x8*>(&tmax[base + 8]) = mx[1];
            *reinterpret_cast<u16x8*>(&tmin[base]) = mn[0];
            *reinterpret_cast<u16x8*>(&tmin[base + 8]) = mn[1];
            __syncthreads();
        }
    } else if (blk < 11) {
        // ---- W fragment pack (full K) ----
        const int layer = blk - 8;
        const float* W = (layer == 0) ? W0 : ((layer == 1) ? W1 : W2);
        const int FRS = (layer == 0) ? 32 : 24;
        const int l = tid & 63;
        for (int fr = tid >> 6; fr < FRS; fr += 8) {
            int kt = fr >> 2, nt = fr & 3;
#pragma unroll
            for (int e = 0; e < 8; ++e) {
                int row = kt * 32 + ((l >> 4) << 3) + e;
                int col = nt * 16 + (l & 15);
                wf[((size_t)(layer * 32 + fr) * 64 + l) * 8 + e] = f2bf(W[row * 64 + col]);
            }
        }
    } else if (blk < 139) {
        // ---- cur0bf: suffix max/min scan over t ----
        const int x = blk - 11;
        const int c = x & 63, b = x >> 6;
        const int t = tid;
        float* smax = reinterpret_cast<float*>(lmax);   // 2 KB
        float* smin = reinterpret_cast<float*>(lmin);
        float v = f[((size_t)(b * T_ + t) << 6) + c];
        smax[t] = v; smin[t] = v;
        __syncthreads();
        for (int off = 1; off < 512; off <<= 1) {
            float a = (t + off < 512) ? smax[t + off] : -1e30f;
            float m = (t + off < 512) ? smin[t + off] : 1e30f;
            __syncthreads();
            smax[t] = fmaxf(smax[t], a);
            smin[t] = fminf(smin[t], m);
            __syncthreads();
        }
        cur0bf[((size_t)(b * T_ + t) << 7) + c] = f2bf(smax[t]);
        cur0bf[((size_t)(b * T_ + t) << 7) + 64 + c] = f2bf(smin[t]);
    } else if (blk < 171) {
        // ---- intra running pools: 5-round inclusive scan over jj ----
        const int x = blk - 139;
        const int jt = x & 15, b = x >> 4;
        const int jj = tid >> 4, c8 = tid & 15;
        const bool ismin = c8 >= 8;
        unsigned short (*sc)[128] = reinterpret_cast<unsigned short (*)[128]>(lmax); // 8 KB

        const float* fp = &f[((size_t)(b * T_ + jt * 32 + jj) << 6) + (c8 & 7) * 8];
        u16x8 r;
#pragma unroll
        for (int e = 0; e < 8; ++e) r[e] = f2bf(fp[e]);

#pragma unroll
        for (int off = 1; off < 32; off <<= 1) {
            *reinterpret_cast<u16x8*>(&sc[jj][c8 * 8]) = r;
            __syncthreads();
            if (jj >= off) {
                u16x8 q = *reinterpret_cast<const u16x8*>(&sc[jj - off][c8 * 8]);
#pragma unroll
                for (int e = 0; e < 8; ++e)
                    r[e] = ismin ? minbits(r[e], q[e]) : maxbits(r[e], q[e]);
            }
            __syncthreads();
        }
        *reinterpret_cast<u16x8*>(&intra[((size_t)((b * 16 + jt) * 32 + jj) << 7) + c8 * 8]) = r;
    } else {
        // ---- zero cur1 / cur2 / out ----
        int fi = (blk - 171) * 512 + tid;   // float4 index, 0..49151
        float4 z = {0.f, 0.f, 0.f, 0.f};
        if (fi < 16384)       reinterpret_cast<float4*>(z0)[fi] = z;
        else if (fi < 32768)  reinterpret_cast<float4*>(z1)[fi - 16384] = z;
        else                  reinterpret_cast<float4*>(z2)[fi - 32768] = z;
    }
}

// ---------------------------------------------------------------------------
// Pair GEMM over triangular tiles.  Block = (b, 4 i's, 32 j's), M=128 N=64.
// K = C + 128: A row p = [ cur(b, j) C ch | rangemax f[i..j] | rangemin ].
// Non-diag staging: contiguous copies of cur0bf / intra tiles + 4 pref queries.
// Diag: per-lane full-range table queries.  Wave w owns i = i0+w entirely.
// ---------------------------------------------------------------------------
template <int C, bool FROM_TAB>
__global__ __launch_bounds__(256) void pair_kernel(
    const unsigned short* __restrict__ tabmax,
    const unsigned short* __restrict__ tabmin,
    const unsigned short* __restrict__ cur0bf,  // [B,T,128] bf16
    const unsigned short* __restrict__ intra,   // [B,16,32,128] bf16
    const float* __restrict__ curprev,          // fp32 [B,T,64]; unused if FROM_TAB
    const unsigned short* __restrict__ wf,      // layer base, fragment order
    const float* __restrict__ bias,
    float* __restrict__ out) {

    constexpr int KTC = C / 32;
    constexpr int KT = KTC + 4;
    constexpr int CP = (C == 128) ? 136 : 72;

    int m = blockIdx.x;
    int b = 0;
    if (m >= NBLK_PER_B) { b = 1; m -= NBLK_PER_B; }
    int jt = 0;
    while (m >= 4 * (jt + 1) * (jt + 2)) ++jt;
    const int it = m - 4 * jt * (jt + 1);
    const bool diag = (it >= 8 * jt);
    const int i0 = it * 4, j0 = jt * 32;

    const int tid = threadIdx.x;
    const int l = tid & 63, w = tid >> 6;
    const int lg = l >> 4, li = l & 15;

    __shared__ unsigned short curl[32][CP];
    __shared__ unsigned short intr[32][136];
    __shared__ unsigned short pref[4][136];

    // ---- stage cur tile [32 j][C ch] as bf16 ----
    if (FROM_TAB) {
#pragma unroll
        for (int q = 0; q < 2; ++q) {
            int chn = q * 256 + tid;
            int jj = chn >> 4, c8 = chn & 15;
            u16x8 v = *reinterpret_cast<const u16x8*>(
                &cur0bf[((size_t)(b * T_ + j0 + jj) << 7) + c8 * 8]);
            *reinterpret_cast<u16x8*>(&curl[jj][c8 * 8]) = v;
        }
    } else {
        int jj = tid >> 3, c8 = tid & 7;
        const float* cp = &curprev[((size_t)(b * T_ + j0 + jj) << 6) + c8 * 8];
        float4 v0 = *reinterpret_cast<const float4*>(cp);
        float4 v1 = *reinterpret_cast<const float4*>(cp + 4);
        u16x8 r;
        r[0] = f2bf(v0.x); r[1] = f2bf(v0.y); r[2] = f2bf(v0.z); r[3] = f2bf(v0.w);
        r[4] = f2bf(v1.x); r[5] = f2bf(v1.y); r[6] = f2bf(v1.z); r[7] = f2bf(v1.w);
        *reinterpret_cast<u16x8*>(&curl[jj][c8 * 8]) = r;
    }

    if (!diag) {
        // ---- intra tile: contiguous copy ----
#pragma unroll
        for (int q = 0; q < 2; ++q) {
            int chn = q * 256 + tid;
            int jj = chn >> 4, c8 = chn & 15;
            u16x8 v = *reinterpret_cast<const u16x8*>(
                &intra[((size_t)((b * 16 + jt) * 32 + jj) << 7) + c8 * 8]);
            *reinterpret_cast<u16x8*>(&intr[jj][c8 * 8]) = v;
        }
        // ---- prefix queries: 4 i's x 16 chunks, range [i, j0-1] ----
        if (tid < 64) {
            int isel = tid >> 4, c8 = tid & 15;
            int i = i0 + isel;
            int len = j0 - i;                  // >= 1 (non-diag)
            int kk = 31 - __clz(len);
            int t2 = j0 - (1 << kk);
            const unsigned short* tab = (c8 < 8) ? tabmax : tabmin;
            int cc = (c8 & 7) * 8;
            u16x8 va = *reinterpret_cast<const u16x8*>(&tab[(((size_t)(kk * B_ + b) * T_ + i) << 6) + cc]);
            u16x8 vb = *reinterpret_cast<const u16x8*>(&tab[(((size_t)(kk * B_ + b) * T_ + t2) << 6) + cc]);
            u16x8 r;
#pragma unroll
            for (int e = 0; e < 8; ++e)
                r[e] = (c8 < 8) ? maxbits(va[e], vb[e]) : minbits(va[e], vb[e]);
            *reinterpret_cast<u16x8*>(&pref[isel][c8 * 8]) = r;
        }
    }
    __syncthreads();

    // ---- GEMM: wave w -> i = i0+w ----
    f32x4 acc[2][4];
#pragma unroll
    for (int s = 0; s < 2; ++s)
#pragma unroll
        for (int nt = 0; nt < 4; ++nt) acc[s][nt] = (f32x4){0.f, 0.f, 0.f, 0.f};

    const int pi = i0 + w;

#pragma unroll
    for (int kt = 0; kt < KT; ++kt) {
        bf16x8 bfr[4];
#pragma unroll
        for (int nt = 0; nt < 4; ++nt)
            bfr[nt] = *reinterpret_cast<const bf16x8*>(&wf[(size_t)((kt * 4 + nt) * 64 + l) * 8]);

#pragma unroll
        for (int s = 0; s < 2; ++s) {
            const int pjj = 16 * s + li;
            bf16x8 av;
            if (kt < KTC) {
                av = *reinterpret_cast<const bf16x8*>(&curl[pjj][kt * 32 + lg * 8]);
            } else {
                const int krt = kt - KTC;
                const int c8 = krt * 4 + lg;
                if (!diag) {
                    u16x8 iv = *reinterpret_cast<const u16x8*>(&intr[pjj][c8 * 8]);
                    u16x8 pv = *reinterpret_cast<const u16x8*>(&pref[w][c8 * 8]);
#pragma unroll
                    for (int e = 0; e < 8; ++e)
                        av[e] = (short)((c8 < 8) ? maxbits(iv[e], pv[e]) : minbits(iv[e], pv[e]));
                } else {
                    const int pj = j0 + pjj;
                    const int je = (pj < pi) ? pi : pj;
                    const int len = je - pi + 1;
                    const int kk = 31 - __clz(len);
                    const int t2 = je + 1 - (1 << kk);
                    const unsigned short* tab = (c8 < 8) ? tabmax : tabmin;
                    const int cc = (c8 & 7) * 8;
                    u16x8 va = *reinterpret_cast<const u16x8*>(&tab[(((size_t)(kk * B_ + b) * T_ + pi) << 6) + cc]);
                    u16x8 vb = *reinterpret_cast<const u16x8*>(&tab[(((size_t)(kk * B_ + b) * T_ + t2) << 6) + cc]);
#pragma unroll
                    for (int e = 0; e < 8; ++e)
                        av[e] = (short)((c8 < 8) ? maxbits(va[e], vb[e]) : minbits(va[e], vb[e]));
                }
            }
#pragma unroll
            for (int nt = 0; nt < 4; ++nt)
                acc[s][nt] = __builtin_amdgcn_mfma_f32_16x16x32_bf16(av, bfr[nt], acc[s][nt], 0, 0, 0);
        }
    }

    // ---- epilogue: wave-local max over jj, +bias, sigmoid, atomicMax ----
#pragma unroll
    for (int nt = 0; nt < 4; ++nt) {
        float vm = -1e9f;
#pragma unroll
        for (int s = 0; s < 2; ++s)
#pragma unroll
            for (int r = 0; r < 4; ++r) {
                int jj = 16 * s + lg * 4 + r;
                if (j0 + jj >= pi) vm = fmaxf(vm, acc[s][nt][r]);
            }
        vm = fmaxf(vm, __shfl_xor(vm, 16));
        vm = fmaxf(vm, __shfl_xor(vm, 32));
        if (l < 16) {
            int o = nt * 16 + li;
            float h = 1.0f / (1.0f + __expf(-(vm + bias[o])));
            atomicMax((int*)out + (((size_t)(b * T_ + pi) << 6) + o), __float_as_int(h));
        }
    }
}

// ---------------------------------------------------------------------------
extern "C" void kernel_launch(void* const* d_in, const int* in_sizes, int n_in,
                              void* d_out, int out_size, void* d_ws, size_t ws_size,
                              hipStream_t stream) {
    const float* f  = (const float*)d_in[0];
    const float* W0 = (const float*)d_in[1];
    const float* b0 = (const float*)d_in[2];
    const float* W1 = (const float*)d_in[3];
    const float* b1 = (const float*)d_in[4];
    const float* W2 = (const float*)d_in[5];
    const float* b2 = (const float*)d_in[6];
    float* outp = (float*)d_out;

    // workspace layout
    unsigned short* tabmax = (unsigned short*)d_ws;               // 10*B*T*64
    unsigned short* tabmin = tabmax + 10 * B_ * T_ * 64;          // 10*B*T*64
    unsigned short* wf     = tabmin + 10 * B_ * T_ * 64;          // 3*32*64*8
    unsigned short* cur0bf = wf + 3 * 32 * 64 * 8;                // B*T*128
    unsigned short* intra  = cur0bf + B_ * T_ * 128;              // B*16*32*128
    float* cur1 = (float*)(intra + B_ * 16 * 32 * 128);           // [B,T,64]
    float* cur2 = cur1 + B_ * T_ * 64;                            // [B,T,64]

    prep_kernel<<<dim3(267), dim3(512), 0, stream>>>(f, W0, W1, W2,
                                                     tabmax, tabmin, wf,
                                                     cur0bf, intra,
                                                     cur1, cur2, outp);

    const dim3 pgrid(B_ * NBLK_PER_B);
    pair_kernel<128, true ><<<pgrid, dim3(256), 0, stream>>>(tabmax, tabmin, cur0bf, intra,
                                                             nullptr, wf + 0 * 32 * 64 * 8, b0, cur1);
    pair_kernel<64,  false><<<pgrid, dim3(256), 0, stream>>>(tabmax, tabmin, cur0bf, intra,
                                                             cur1, wf + 1 * 32 * 64 * 8, b1, cur2);
    pair_kernel<64,  false><<<pgrid, dim3(256), 0, stream>>>(tabmax, tabmin, cur0bf, intra,
                                                             cur2, wf + 2 * 32 * 64 * 8, b2, outp);
}